// Round 4
// baseline (211.725 us; speedup 1.0000x reference)
//
#include <hip/hip_runtime.h>
#include <hip/hip_bf16.h>

// ---------------- types ----------------
typedef __bf16 bf16x8 __attribute__((__ext_vector_type__(8)));
typedef __bf16 bf16x4 __attribute__((__ext_vector_type__(4)));
typedef float  f32x4  __attribute__((__ext_vector_type__(4)));

#define MFMA16(a, b, c) __builtin_amdgcn_mfma_f32_16x16x32_bf16((a), (b), (c), 0, 0, 0)

static constexpr int   NSEQ  = 2304;   // 48*48
static constexpr float SCALE = 0.17677669529663687f;  // 32^-0.5
static constexpr int   KVS   = 6;      // kv split factor

// XOR swizzle for [rows][256] bf16 LDS tiles (row stride 512B).
#define SWZ(row, colByte) ((row) * 512 + ((colByte) ^ (((row) & 7) << 4)))

// ---------------- weight transpose + f32->bf16 (+ bias table transpose) ----------------
__global__ __launch_bounds__(256) void prep_kernel(
    const float* __restrict__ wqkv, const float* __restrict__ wproj,
    const float* __restrict__ wfc1, const float* __restrict__ wfc2,
    const float* __restrict__ btab,
    __hip_bfloat16* __restrict__ oqkv, __hip_bfloat16* __restrict__ oproj,
    __hip_bfloat16* __restrict__ ofc1, __hip_bfloat16* __restrict__ ofc2,
    float* __restrict__ btabT)
{
    int b = blockIdx.x;
    int tid = threadIdx.x;
    if (b >= 768) {   // bias table [9025][8] -> [8][9025]
        int base = (b - 768) * 1024;
        for (int k = tid; k < 1024; k += 256) {
            int e = base + k;
            if (e < 72200) { int i = e >> 3, hh = e & 7; btabT[hh * 9025 + i] = btab[e]; }
        }
        return;
    }
    const float* src; __hip_bfloat16* dst; int K, N, t;
    if (b < 192)      { src = wqkv;  dst = oqkv;  K = 256;  N = 768;  t = b;       }
    else if (b < 256) { src = wproj; dst = oproj; K = 256;  N = 256;  t = b - 192; }
    else if (b < 512) { src = wfc1;  dst = ofc1;  K = 256;  N = 1024; t = b - 256; }
    else              { src = wfc2;  dst = ofc2;  K = 1024; N = 256;  t = b - 512; }
    int ntn = N >> 5;
    int tk = t / ntn, tn = t % ntn;
    __shared__ float tile[32][33];
    int tx = tid & 31, ty = tid >> 5;   // 32 x 8
    #pragma unroll
    for (int r = 0; r < 4; ++r)
        tile[ty + 8 * r][tx] = src[(size_t)(tk * 32 + ty + 8 * r) * N + tn * 32 + tx];
    __syncthreads();
    #pragma unroll
    for (int r = 0; r < 4; ++r)
        dst[(size_t)(tn * 32 + ty + 8 * r) * K + tk * 32 + tx] =
            __float2bfloat16(tile[tx][ty + 8 * r]);
}

// ---------------- fused LN1 + QKV GEMM ----------------
// grid (12, 72): 32 rows x 64 cols of [Q|K|V]. 4 waves, depth-2 B pipeline.
__global__ __launch_bounds__(256) void qkv_ln_kernel(
    const float* __restrict__ x, const float* __restrict__ g1,
    const float* __restrict__ b1, const __hip_bfloat16* __restrict__ BT,
    __hip_bfloat16* __restrict__ Qb, __hip_bfloat16* __restrict__ Kb,
    __hip_bfloat16* __restrict__ Vt)
{
    __shared__ char smem[32 * 512];    // A-tile [32][256] bf16 swizzled; V blocks reuse
    int tid = threadIdx.x;
    int bn = blockIdx.x * 64, bm = blockIdx.y * 32;

    // --- LN prologue: 8 lanes per row ---
    {
        int row = tid >> 3, part = tid & 7;
        const float* xr = x + (size_t)(bm + row) * 256 + part * 32;
        float vals[32];
        float s = 0.f, s2 = 0.f;
        #pragma unroll
        for (int i = 0; i < 8; ++i) {
            f32x4 v4 = *reinterpret_cast<const f32x4*>(xr + 4 * i);
            #pragma unroll
            for (int e = 0; e < 4; ++e) {
                vals[4 * i + e] = v4[e];
                s += v4[e]; s2 += v4[e] * v4[e];
            }
        }
        s  += __shfl_xor(s, 1);  s  += __shfl_xor(s, 2);  s  += __shfl_xor(s, 4);
        s2 += __shfl_xor(s2, 1); s2 += __shfl_xor(s2, 2); s2 += __shfl_xor(s2, 4);
        float mu   = s * (1.f / 256.f);
        float var  = s2 * (1.f / 256.f) - mu * mu;
        float rstd = rsqrtf(var + 1e-5f);
        #pragma unroll
        for (int i = 0; i < 8; ++i) {
            int c = part * 32 + 4 * i;
            f32x4 gv = *reinterpret_cast<const f32x4*>(g1 + c);
            f32x4 bv = *reinterpret_cast<const f32x4*>(b1 + c);
            bf16x4 pk;
            #pragma unroll
            for (int e = 0; e < 4; ++e)
                pk[e] = (__bf16)((vals[4 * i + e] - mu) * rstd * gv[e] + bv[e]);
            *reinterpret_cast<bf16x4*>(smem + SWZ(row, c * 2)) = pk;
        }
    }
    __syncthreads();

    // --- GEMM: waves 2x2 over (32 rows x 64 cols), FM=1, FN=2 ---
    int w = tid >> 6, lane = tid & 63, l15 = lane & 15, g = lane >> 4;
    int wr = w >> 1, wc = w & 1;
    f32x4 acc[2];
    acc[0] = (f32x4){0.f, 0.f, 0.f, 0.f};
    acc[1] = (f32x4){0.f, 0.f, 0.f, 0.f};
    const __hip_bfloat16* Brow = BT + (size_t)(bn + wc * 32 + l15) * 256 + 8 * g;
    bf16x8 p0[2][2], p1[2][2];   // [ks][fj]

#define QLOADB(dst, kb) { \
    _Pragma("unroll") for (int ks = 0; ks < 2; ++ks) \
    _Pragma("unroll") for (int fj = 0; fj < 2; ++fj) \
        dst[ks][fj] = *reinterpret_cast<const bf16x8*>(Brow + (size_t)16 * fj * 256 + (kb) + 32 * ks); }
#define QCOMP(src, kb) { \
    _Pragma("unroll") for (int ks = 0; ks < 2; ++ks) { \
        bf16x8 af = *reinterpret_cast<const bf16x8*>(smem + SWZ(wr * 16 + l15, 2 * ((kb) + 32 * ks + 8 * g))); \
        _Pragma("unroll") for (int fj = 0; fj < 2; ++fj) \
            acc[fj] = MFMA16(af, src[ks][fj], acc[fj]); } }

    QLOADB(p0, 0);
    QLOADB(p1, 64);
    QCOMP(p0, 0);
    QLOADB(p0, 128);
    QCOMP(p1, 64);
    QLOADB(p1, 192);
    QCOMP(p0, 128);
    QCOMP(p1, 192);
#undef QLOADB
#undef QCOMP

    // --- epilogue ---
    if (bn >= 512) {   // V: LDS transpose for coalesced [h][d][n] stores
        __syncthreads();
        float* vtile = (float*)smem;   // [32][65]
        #pragma unroll
        for (int fj = 0; fj < 2; ++fj)
        #pragma unroll
        for (int j = 0; j < 4; ++j)
            vtile[(wr * 16 + 4 * g + j) * 65 + wc * 32 + 16 * fj + l15] = acc[fj][j];
        __syncthreads();
        for (int e = tid; e < 2048; e += 256) {
            int mi = e & 31, ni = e >> 5;
            int n = bn + ni;
            int h = (n >> 5) & 7, d = n & 31;
            Vt[(size_t)(h * 32 + d) * NSEQ + bm + mi] = __float2bfloat16(vtile[mi * 65 + ni]);
        }
        return;
    }
    #pragma unroll
    for (int fj = 0; fj < 2; ++fj)
    #pragma unroll
    for (int j = 0; j < 4; ++j) {
        int m = bm + wr * 16 + 4 * g + j;
        int n = bn + wc * 32 + 16 * fj + l15;
        float v = acc[fj][j];
        int which = n >> 8, h = (n >> 5) & 7, d = n & 31;
        if (which == 0) Qb[((size_t)(h * NSEQ + m) << 5) + d] = __float2bfloat16(v * SCALE);
        else            Kb[((size_t)(h * NSEQ + m) << 5) + d] = __float2bfloat16(v);
    }
}

// ---------------- flash attention, kv split 6 ways across blocks ----------------
__global__ __launch_bounds__(256) void attn_kernel(
    const __hip_bfloat16* __restrict__ Q,
    const __hip_bfloat16* __restrict__ Kb,
    const __hip_bfloat16* __restrict__ Vt,     // [8][32][2304]
    const float* __restrict__ btabT,           // [8][9025]
    float* __restrict__ Pm, float* __restrict__ Pl,
    __hip_bfloat16* __restrict__ PO)           // [6][8][2304][32]
{
    __shared__ float bias_l[10 * 96];
    __shared__ __hip_bfloat16 P_lds[4][16][72];

    int bid = blockIdx.x;
    int h = bid / (36 * KVS);
    int r = bid - h * (36 * KVS);
    int qt = r / KVS, kvq = r - qt * KVS;
    int tid = threadIdx.x;
    int w = tid >> 6, lane = tid & 63, l15 = lane & 15, g = lane >> 4;

    int q0 = qt * 64;
    int i1min = q0 / 48, i1max = (q0 + 63) / 48;
    int i2min = kvq * 8;
    int dimin = i1min - (i2min + 7);
    int nrow = (i1max - i1min) + 8;      // <= 9

    for (int i = tid; i < nrow * 95; i += 256) {
        int rr = i / 95, cc = i - rr * 95;
        bias_l[rr * 96 + cc] = btabT[h * 9025 + (dimin + rr + 47) * 95 + cc];
    }
    __syncthreads();

    int qrow = q0 + w * 16 + l15;
    int i1 = qrow / 48, j1 = qrow - i1 * 48;
    int laneBase = (i1 - dimin) * 96 + j1 + 47;
    bf16x8 qf = *reinterpret_cast<const bf16x8*>(Q + ((size_t)(h * NSEQ + qrow) << 5) + 8 * g);

    float m_st = -1e30f, l_st = 0.f;
    f32x4 o0 = (f32x4){0.f, 0.f, 0.f, 0.f};
    f32x4 o1 = (f32x4){0.f, 0.f, 0.f, 0.f};
    const f32x4 zero = (f32x4){0.f, 0.f, 0.f, 0.f};
    int kvbase = kvq * 384;

    for (int t = 0; t < 6; ++t) {
        int kv0 = kvbase + t * 64;
        bf16x8 vf[4];
        #pragma unroll
        for (int u = 0; u < 4; ++u) {
            int dt = u >> 1, hh = u & 1;
            vf[u] = *reinterpret_cast<const bf16x8*>(
                Vt + (size_t)((h << 5) + 16 * dt + l15) * NSEQ + kv0 + 32 * hh + 8 * g);
        }
        f32x4 st[4];
        __builtin_amdgcn_s_setprio(1);
        #pragma unroll
        for (int s = 0; s < 4; ++s) {
            bf16x8 kf = *reinterpret_cast<const bf16x8*>(
                Kb + ((size_t)(h * NSEQ + kv0 + 16 * s + l15) << 5) + 8 * g);
            st[s] = MFMA16(kf, qf, zero);   // S^T[kv][q]
        }
        __builtin_amdgcn_s_setprio(0);
        float mx = -1e30f;
        #pragma unroll
        for (int s = 0; s < 4; ++s) {
            int kvb = kv0 + 16 * s + 4 * g;
            int i2 = kvb / 48;
            int j2b = kvb - 48 * i2;
            int sub = laneBase - i2 * 96 - j2b;
            #pragma unroll
            for (int j = 0; j < 4; ++j) {
                int idx = sub - j - ((j2b + j >= 48) ? 48 : 0);
                float sv = st[s][j] + bias_l[idx];
                st[s][j] = sv;
                mx = fmaxf(mx, sv);
            }
        }
        mx = fmaxf(mx, __shfl_xor(mx, 16));
        mx = fmaxf(mx, __shfl_xor(mx, 32));
        float mn = fmaxf(m_st, mx);
        float rs = 0.f;
        #pragma unroll
        for (int s = 0; s < 4; ++s)
            #pragma unroll
            for (int j = 0; j < 4; ++j) {
                float e = __expf(st[s][j] - mn);
                st[s][j] = e;
                rs += e;
            }
        rs += __shfl_xor(rs, 16);
        rs += __shfl_xor(rs, 32);
        float sc = __expf(m_st - mn);
        l_st = l_st * sc + rs;
        m_st = mn;
        float scr[4];
        #pragma unroll
        for (int j = 0; j < 4; ++j) scr[j] = __shfl(sc, 4 * g + j);
        #pragma unroll
        for (int j = 0; j < 4; ++j) { o0[j] *= scr[j]; o1[j] *= scr[j]; }
        #pragma unroll
        for (int s = 0; s < 4; ++s) {
            bf16x4 pk = { (__bf16)st[s][0], (__bf16)st[s][1], (__bf16)st[s][2], (__bf16)st[s][3] };
            *reinterpret_cast<bf16x4*>(&P_lds[w][l15][16 * s + 4 * g]) = pk;
        }
        __builtin_amdgcn_s_setprio(1);
        #pragma unroll
        for (int hh = 0; hh < 2; ++hh) {
            bf16x8 pf = *reinterpret_cast<const bf16x8*>(&P_lds[w][l15][32 * hh + 8 * g]);
            o0 = MFMA16(pf, vf[hh], o0);
            o1 = MFMA16(pf, vf[2 + hh], o1);
        }
        __builtin_amdgcn_s_setprio(0);
    }

    size_t mb = (size_t)(kvq * 8 + h) * NSEQ;
    if (g == 0) { Pm[mb + qrow] = m_st; Pl[mb + qrow] = l_st; }
    #pragma unroll
    for (int dt = 0; dt < 2; ++dt)
        #pragma unroll
        for (int j = 0; j < 4; ++j) {
            int row = q0 + w * 16 + 4 * g + j;
            PO[(mb + row) * 32 + 16 * dt + l15] =
                __float2bfloat16(dt == 0 ? o0[j] : o1[j]);
        }
}

// ---------------- fused merge + proj + residual + LN2 ----------------
// grid 144 blocks (16 rows each), 512 thr = 8 waves, depth-2 B pipeline.
__global__ __launch_bounds__(512) void proj_kernel(
    const __hip_bfloat16* __restrict__ PO, const float* __restrict__ Pm,
    const float* __restrict__ Pl, const __hip_bfloat16* __restrict__ BT,
    const float* __restrict__ bproj, const float* __restrict__ x,
    const float* __restrict__ g2, const float* __restrict__ b2,
    float* __restrict__ x2, __hip_bfloat16* __restrict__ t2)
{
    __shared__ char smem[16 * 512];    // merged A-tile [16][256] bf16 swizzled
    __shared__ float redS[8][16], redQ[8][16], muA[16], rsA[16];
    int tid = threadIdx.x;
    int q0 = blockIdx.x * 16;

    // --- merge prologue ---
    {
        int row = tid >> 5;            // 0..15
        int c0  = (tid & 31) * 8;
        int h = c0 >> 5, d = c0 & 31;
        float m[KVS], l[KVS], a[KVS];
        #pragma unroll
        for (int k = 0; k < KVS; ++k) {
            size_t mb = (size_t)(k * 8 + h) * NSEQ + q0 + row;
            m[k] = Pm[mb]; l[k] = Pl[mb];
        }
        float M = m[0];
        #pragma unroll
        for (int k = 1; k < KVS; ++k) M = fmaxf(M, m[k]);
        float L = 0.f;
        #pragma unroll
        for (int k = 0; k < KVS; ++k) { a[k] = __expf(m[k] - M); L += a[k] * l[k]; }
        float inv = 1.f / L;
        float o[8] = {0.f, 0.f, 0.f, 0.f, 0.f, 0.f, 0.f, 0.f};
        #pragma unroll
        for (int k = 0; k < KVS; ++k) {
            bf16x8 po = *reinterpret_cast<const bf16x8*>(
                PO + ((size_t)(k * 8 + h) * NSEQ + q0 + row) * 32 + d);
            #pragma unroll
            for (int e = 0; e < 8; ++e) o[e] += a[k] * (float)po[e];
        }
        bf16x8 pk;
        #pragma unroll
        for (int e = 0; e < 8; ++e) pk[e] = (__bf16)(o[e] * inv);
        *reinterpret_cast<bf16x8*>(smem + SWZ(row, c0 * 2)) = pk;
    }
    __syncthreads();

    // --- GEMM: wave w covers cols w*32..+31 (FM=1, FN=2) ---
    int w = tid >> 6, lane = tid & 63, l15 = lane & 15, g = lane >> 4;
    f32x4 acc[2];
    acc[0] = (f32x4){0.f, 0.f, 0.f, 0.f};
    acc[1] = (f32x4){0.f, 0.f, 0.f, 0.f};
    const __hip_bfloat16* Brow = BT + (size_t)(w * 32 + l15) * 256 + 8 * g;
    bf16x8 p0[2][2], p1[2][2];

#define PLOADB(dst, kb) { \
    _Pragma("unroll") for (int ks = 0; ks < 2; ++ks) \
    _Pragma("unroll") for (int fj = 0; fj < 2; ++fj) \
        dst[ks][fj] = *reinterpret_cast<const bf16x8*>(Brow + (size_t)16 * fj * 256 + (kb) + 32 * ks); }
#define PCOMP(src, kb) { \
    _Pragma("unroll") for (int ks = 0; ks < 2; ++ks) { \
        bf16x8 af = *reinterpret_cast<const bf16x8*>(smem + SWZ(l15, 2 * ((kb) + 32 * ks + 8 * g))); \
        _Pragma("unroll") for (int fj = 0; fj < 2; ++fj) \
            acc[fj] = MFMA16(af, src[ks][fj], acc[fj]); } }

    PLOADB(p0, 0);
    PLOADB(p1, 64);
    PCOMP(p0, 0);
    PLOADB(p0, 128);
    PCOMP(p1, 64);
    PLOADB(p1, 192);
    PCOMP(p0, 128);
    PCOMP(p1, 192);
#undef PLOADB
#undef PCOMP

    // --- epilogue: residual + LN2 ---
    float rr[2][4];
    float s[4] = {0.f, 0.f, 0.f, 0.f}, sq[4] = {0.f, 0.f, 0.f, 0.f};
    #pragma unroll
    for (int fj = 0; fj < 2; ++fj)
        #pragma unroll
        for (int j = 0; j < 4; ++j) {
            int mrow = 4 * g + j;
            int n = w * 32 + 16 * fj + l15;
            float v = acc[fj][j] + bproj[n] + x[(size_t)(q0 + mrow) * 256 + n];
            x2[(size_t)(q0 + mrow) * 256 + n] = v;
            rr[fj][j] = v;
            s[j] += v; sq[j] += v * v;
        }
    #pragma unroll
    for (int mask = 1; mask <= 8; mask <<= 1)
        #pragma unroll
        for (int j = 0; j < 4; ++j) {
            s[j]  += __shfl_xor(s[j],  mask);
            sq[j] += __shfl_xor(sq[j], mask);
        }
    if (l15 == 0)
        #pragma unroll
        for (int j = 0; j < 4; ++j) { redS[w][4 * g + j] = s[j]; redQ[w][4 * g + j] = sq[j]; }
    __syncthreads();
    if (tid < 16) {
        float S = 0.f, Qq = 0.f;
        #pragma unroll
        for (int ww = 0; ww < 8; ++ww) { S += redS[ww][tid]; Qq += redQ[ww][tid]; }
        float mu = S * (1.f / 256.f);
        float var = Qq * (1.f / 256.f) - mu * mu;
        muA[tid] = mu;
        rsA[tid] = rsqrtf(var + 1e-5f);
    }
    __syncthreads();
    #pragma unroll
    for (int fj = 0; fj < 2; ++fj)
        #pragma unroll
        for (int j = 0; j < 4; ++j) {
            int mrow = 4 * g + j;
            int n = w * 32 + 16 * fj + l15;
            float tv = (rr[fj][j] - muA[mrow]) * rsA[mrow] * g2[n] + b2[n];
            t2[(size_t)(q0 + mrow) * 256 + n] = __float2bfloat16(tv);
        }
}

// ---------------- MLP GEMMs, depth-2 pipelined, per-block K = 256 ----------------
// EPI 2: fc1 + bias + gelu (bf16 out) + d_out prefill (bx==0)
// EPI 3: fc2 split-K partial, atomicAdd f32 into prefilled d_out
template <int EPI, int NN, int KTOT, int FM, int FN, int WR, int WC>
__global__ __launch_bounds__(256) void gemm_kernel(
    const __hip_bfloat16* __restrict__ A,
    const __hip_bfloat16* __restrict__ BT,
    const float* __restrict__ bias,
    const float* __restrict__ resid,
    const float* __restrict__ bias2,
    void* __restrict__ out0,
    float* __restrict__ outPre)
{
    constexpr int BM = WR * FM * 16, BN = WC * FN * 16;
    int bm = blockIdx.y * BM, bn = blockIdx.x * BN;
    int k0 = blockIdx.z * 256;
    int tid = threadIdx.x;
    int w = tid >> 6, lane = tid & 63, l15 = lane & 15, g = lane >> 4;
    int wr = w / WC, wc = w % WC;

    if constexpr (EPI == 2) {   // prefill d_out = x2 + b_fc2 (bx==0 blocks only)
        if (blockIdx.x == 0) {
            for (int e = tid; e < BM * 64; e += 256) {
                int mi = e >> 6, c4 = (e & 63) << 2;
                f32x4 xv = *reinterpret_cast<const f32x4*>(resid + (size_t)(bm + mi) * 256 + c4);
                f32x4 bv = *reinterpret_cast<const f32x4*>(bias2 + c4);
                *reinterpret_cast<f32x4*>(outPre + (size_t)(bm + mi) * 256 + c4) = xv + bv;
            }
        }
    }

    f32x4 acc[FM][FN];
    #pragma unroll
    for (int i = 0; i < FM; ++i)
        #pragma unroll
        for (int j = 0; j < FN; ++j) acc[i][j] = (f32x4){0.f, 0.f, 0.f, 0.f};

    const __hip_bfloat16* Arow = A  + (size_t)(bm + wr * FM * 16 + l15) * KTOT + k0 + 8 * g;
    const __hip_bfloat16* Brow = BT + (size_t)(bn + wc * FN * 16 + l15) * KTOT + k0 + 8 * g;

    bf16x8 a0[2][FM], b0[2][FN], a1[2][FM], b1[2][FN];

#define GLOAD(ar, br, kb) { \
    _Pragma("unroll") for (int ks = 0; ks < 2; ++ks) { \
        _Pragma("unroll") for (int i = 0; i < FM; ++i) \
            ar[ks][i] = *reinterpret_cast<const bf16x8*>(Arow + (size_t)16 * i * KTOT + (kb) + 32 * ks); \
        _Pragma("unroll") for (int j2 = 0; j2 < FN; ++j2) \
            br[ks][j2] = *reinterpret_cast<const bf16x8*>(Brow + (size_t)16 * j2 * KTOT + (kb) + 32 * ks); } }
#define GCOMP(ar, br) { \
    _Pragma("unroll") for (int ks = 0; ks < 2; ++ks) \
        _Pragma("unroll") for (int i = 0; i < FM; ++i) \
            _Pragma("unroll") for (int j2 = 0; j2 < FN; ++j2) \
                acc[i][j2] = MFMA16(ar[ks][i], br[ks][j2], acc[i][j2]); }

    GLOAD(a0, b0, 0);
    GLOAD(a1, b1, 64);
    GCOMP(a0, b0);
    GLOAD(a0, b0, 128);
    GCOMP(a1, b1);
    GLOAD(a1, b1, 192);
    GCOMP(a0, b0);
    GCOMP(a1, b1);
#undef GLOAD
#undef GCOMP

    #pragma unroll
    for (int fi = 0; fi < FM; ++fi)
    #pragma unroll
    for (int fj = 0; fj < FN; ++fj)
    #pragma unroll
    for (int j = 0; j < 4; ++j) {
        int m = bm + wr * FM * 16 + 16 * fi + 4 * g + j;
        int n = bn + wc * FN * 16 + 16 * fj + l15;
        float v = acc[fi][fj][j];
        if constexpr (EPI == 2) {
            float r = v + bias[n];
            r = 0.5f * r * (1.f + erff(r * 0.70710678118654752f));
            ((__hip_bfloat16*)out0)[(size_t)m * NN + n] = __float2bfloat16(r);
        } else {
            atomicAdd((float*)out0 + (size_t)m * 256 + n, v);
        }
    }
}

// ---------------- launch ----------------
extern "C" void kernel_launch(void* const* d_in, const int* in_sizes, int n_in,
                              void* d_out, int out_size, void* d_ws, size_t ws_size,
                              hipStream_t stream)
{
    const float* x      = (const float*)d_in[0];
    const float* gamma1 = (const float*)d_in[1];
    const float* beta1  = (const float*)d_in[2];
    const float* w_qkv  = (const float*)d_in[3];
    const float* w_proj = (const float*)d_in[4];
    const float* b_proj = (const float*)d_in[5];
    const float* btab   = (const float*)d_in[6];
    const float* gamma2 = (const float*)d_in[7];
    const float* beta2  = (const float*)d_in[8];
    const float* w_fc1  = (const float*)d_in[9];
    const float* b_fc1  = (const float*)d_in[10];
    const float* w_fc2  = (const float*)d_in[11];
    const float* b_fc2  = (const float*)d_in[12];
    // d_in[13] rel_idx: recomputed analytically in-kernel.

    char* ws = (char*)d_ws;
    size_t off = 0;
    auto alloc = [&](size_t bytes) -> void* {
        void* p = ws + off;
        off += (bytes + 255) & ~(size_t)255;
        return p;
    };
    __hip_bfloat16* wqkvT = (__hip_bfloat16*)alloc((size_t)768 * 256 * 2);
    __hip_bfloat16* wprojT= (__hip_bfloat16*)alloc((size_t)256 * 256 * 2);
    __hip_bfloat16* wfc1T = (__hip_bfloat16*)alloc((size_t)1024 * 256 * 2);
    __hip_bfloat16* wfc2T = (__hip_bfloat16*)alloc((size_t)256 * 1024 * 2);
    float*          btabT = (float*)alloc((size_t)8 * 9025 * 4);
    __hip_bfloat16* Qb    = (__hip_bfloat16*)alloc((size_t)8 * NSEQ * 32 * 2);
    __hip_bfloat16* Kbuf  = (__hip_bfloat16*)alloc((size_t)8 * NSEQ * 32 * 2);
    __hip_bfloat16* Vt    = (__hip_bfloat16*)alloc((size_t)8 * 32 * NSEQ * 2);
    float*          x2    = (float*)alloc((size_t)NSEQ * 256 * 4);
    __hip_bfloat16* t2    = (__hip_bfloat16*)alloc((size_t)NSEQ * 256 * 2);
    float*          Pm    = (float*)alloc((size_t)KVS * 8 * NSEQ * 4);
    float*          Pl    = (float*)alloc((size_t)KVS * 8 * NSEQ * 4);
    __hip_bfloat16* PO    = (__hip_bfloat16*)alloc((size_t)KVS * 8 * NSEQ * 32 * 2);
    __hip_bfloat16* hb    = (__hip_bfloat16*)alloc((size_t)NSEQ * 1024 * 2);

    prep_kernel<<<dim3(839), dim3(256), 0, stream>>>(
        w_qkv, w_proj, w_fc1, w_fc2, btab, wqkvT, wprojT, wfc1T, wfc2T, btabT);

    qkv_ln_kernel<<<dim3(12, 72), dim3(256), 0, stream>>>(
        x, gamma1, beta1, wqkvT, Qb, Kbuf, Vt);

    attn_kernel<<<dim3(8 * 36 * KVS), dim3(256), 0, stream>>>(
        Qb, Kbuf, Vt, btabT, Pm, Pl, PO);

    proj_kernel<<<dim3(144), dim3(512), 0, stream>>>(
        PO, Pm, Pl, wprojT, b_proj, x, gamma2, beta2, x2, t2);

    // fc1: M=2304 N=1024 K=256, 64x32 blocks, 4 waves (FM=2, FN=1)
    gemm_kernel<2, 1024, 256, 2, 1, 2, 2><<<dim3(32, 36), dim3(256), 0, stream>>>(
        t2, wfc1T, b_fc1, x2, b_fc2, hb, (float*)d_out);

    // fc2: M=2304 N=256 K=1024 split 4, 64x16 blocks, 4 waves (FM=1, FN=1)
    gemm_kernel<3, 256, 1024, 1, 1, 4, 1><<<dim3(16, 36, 4), dim3(256), 0, stream>>>(
        hb, wfc2T, b_fc2, nullptr, nullptr, d_out, nullptr);
}

// Round 5
// 207.297 us; speedup vs baseline: 1.0214x; 1.0214x over previous
//
#include <hip/hip_runtime.h>
#include <hip/hip_bf16.h>

// ---------------- types ----------------
typedef __bf16 bf16x8 __attribute__((__ext_vector_type__(8)));
typedef __bf16 bf16x4 __attribute__((__ext_vector_type__(4)));
typedef float  f32x4  __attribute__((__ext_vector_type__(4)));

#define MFMA16(a, b, c) __builtin_amdgcn_mfma_f32_16x16x32_bf16((a), (b), (c), 0, 0, 0)

static constexpr int   NSEQ  = 2304;   // 48*48
static constexpr float SCALE = 0.17677669529663687f;  // 32^-0.5
static constexpr float LOG2E = 1.44269504088896340736f;
static constexpr int   KVS   = 6;      // kv split factor
static constexpr float DEFER_THR = 11.5f;  // log2-domain defer-max threshold

// XOR swizzle for [rows][256] bf16 LDS tiles (row stride 512B).
#define SWZ(row, colByte) ((row) * 512 + ((colByte) ^ (((row) & 7) << 4)))

// ---------------- weight transpose + f32->bf16 (+ bias table transpose) ----------------
__global__ __launch_bounds__(256) void prep_kernel(
    const float* __restrict__ wqkv, const float* __restrict__ wproj,
    const float* __restrict__ wfc1, const float* __restrict__ wfc2,
    const float* __restrict__ btab,
    __hip_bfloat16* __restrict__ oqkv, __hip_bfloat16* __restrict__ oproj,
    __hip_bfloat16* __restrict__ ofc1, __hip_bfloat16* __restrict__ ofc2,
    float* __restrict__ btabT)
{
    int b = blockIdx.x;
    int tid = threadIdx.x;
    if (b >= 768) {   // bias table [9025][8] -> [8][9025], pre-scaled to log2 domain
        int base = (b - 768) * 1024;
        for (int k = tid; k < 1024; k += 256) {
            int e = base + k;
            if (e < 72200) { int i = e >> 3, hh = e & 7; btabT[hh * 9025 + i] = btab[e] * LOG2E; }
        }
        return;
    }
    const float* src; __hip_bfloat16* dst; int K, N, t;
    if (b < 192)      { src = wqkv;  dst = oqkv;  K = 256;  N = 768;  t = b;       }
    else if (b < 256) { src = wproj; dst = oproj; K = 256;  N = 256;  t = b - 192; }
    else if (b < 512) { src = wfc1;  dst = ofc1;  K = 256;  N = 1024; t = b - 256; }
    else              { src = wfc2;  dst = ofc2;  K = 1024; N = 256;  t = b - 512; }
    int ntn = N >> 5;
    int tk = t / ntn, tn = t % ntn;
    __shared__ float tile[32][33];
    int tx = tid & 31, ty = tid >> 5;   // 32 x 8
    #pragma unroll
    for (int r = 0; r < 4; ++r)
        tile[ty + 8 * r][tx] = src[(size_t)(tk * 32 + ty + 8 * r) * N + tn * 32 + tx];
    __syncthreads();
    #pragma unroll
    for (int r = 0; r < 4; ++r)
        dst[(size_t)(tn * 32 + ty + 8 * r) * K + tk * 32 + tx] =
            __float2bfloat16(tile[tx][ty + 8 * r]);
}

// ---------------- fused LN1 + QKV GEMM ----------------
// grid (12, 72): 32 rows x 64 cols of [Q|K|V]. 4 waves, depth-2 B pipeline.
__global__ __launch_bounds__(256) void qkv_ln_kernel(
    const float* __restrict__ x, const float* __restrict__ g1,
    const float* __restrict__ b1, const __hip_bfloat16* __restrict__ BT,
    __hip_bfloat16* __restrict__ Qb, __hip_bfloat16* __restrict__ Kb,
    __hip_bfloat16* __restrict__ Vt)
{
    __shared__ char smem[32 * 512];    // A-tile [32][256] bf16 swizzled; V blocks reuse
    int tid = threadIdx.x;
    int bn = blockIdx.x * 64, bm = blockIdx.y * 32;

    // --- LN prologue: 8 lanes per row ---
    {
        int row = tid >> 3, part = tid & 7;
        const float* xr = x + (size_t)(bm + row) * 256 + part * 32;
        float vals[32];
        float s = 0.f, s2 = 0.f;
        #pragma unroll
        for (int i = 0; i < 8; ++i) {
            f32x4 v4 = *reinterpret_cast<const f32x4*>(xr + 4 * i);
            #pragma unroll
            for (int e = 0; e < 4; ++e) {
                vals[4 * i + e] = v4[e];
                s += v4[e]; s2 += v4[e] * v4[e];
            }
        }
        s  += __shfl_xor(s, 1);  s  += __shfl_xor(s, 2);  s  += __shfl_xor(s, 4);
        s2 += __shfl_xor(s2, 1); s2 += __shfl_xor(s2, 2); s2 += __shfl_xor(s2, 4);
        float mu   = s * (1.f / 256.f);
        float var  = s2 * (1.f / 256.f) - mu * mu;
        float rstd = rsqrtf(var + 1e-5f);
        #pragma unroll
        for (int i = 0; i < 8; ++i) {
            int c = part * 32 + 4 * i;
            f32x4 gv = *reinterpret_cast<const f32x4*>(g1 + c);
            f32x4 bv = *reinterpret_cast<const f32x4*>(b1 + c);
            bf16x4 pk;
            #pragma unroll
            for (int e = 0; e < 4; ++e)
                pk[e] = (__bf16)((vals[4 * i + e] - mu) * rstd * gv[e] + bv[e]);
            *reinterpret_cast<bf16x4*>(smem + SWZ(row, c * 2)) = pk;
        }
    }
    __syncthreads();

    // --- GEMM: waves 2x2 over (32 rows x 64 cols), FM=1, FN=2 ---
    int w = tid >> 6, lane = tid & 63, l15 = lane & 15, g = lane >> 4;
    int wr = w >> 1, wc = w & 1;
    f32x4 acc[2];
    acc[0] = (f32x4){0.f, 0.f, 0.f, 0.f};
    acc[1] = (f32x4){0.f, 0.f, 0.f, 0.f};
    const __hip_bfloat16* Brow = BT + (size_t)(bn + wc * 32 + l15) * 256 + 8 * g;
    bf16x8 p0[2][2], p1[2][2];   // [ks][fj]

#define QLOADB(dst, kb) { \
    _Pragma("unroll") for (int ks = 0; ks < 2; ++ks) \
    _Pragma("unroll") for (int fj = 0; fj < 2; ++fj) \
        dst[ks][fj] = *reinterpret_cast<const bf16x8*>(Brow + (size_t)16 * fj * 256 + (kb) + 32 * ks); }
#define QCOMP(src, kb) { \
    _Pragma("unroll") for (int ks = 0; ks < 2; ++ks) { \
        bf16x8 af = *reinterpret_cast<const bf16x8*>(smem + SWZ(wr * 16 + l15, 2 * ((kb) + 32 * ks + 8 * g))); \
        _Pragma("unroll") for (int fj = 0; fj < 2; ++fj) \
            acc[fj] = MFMA16(af, src[ks][fj], acc[fj]); } }

    QLOADB(p0, 0);
    QLOADB(p1, 64);
    QCOMP(p0, 0);
    QLOADB(p0, 128);
    QCOMP(p1, 64);
    QLOADB(p1, 192);
    QCOMP(p0, 128);
    QCOMP(p1, 192);
#undef QLOADB
#undef QCOMP

    // --- epilogue ---
    if (bn >= 512) {   // V: LDS transpose for coalesced [h][d][n] stores
        __syncthreads();
        float* vtile = (float*)smem;   // [32][65]
        #pragma unroll
        for (int fj = 0; fj < 2; ++fj)
        #pragma unroll
        for (int j = 0; j < 4; ++j)
            vtile[(wr * 16 + 4 * g + j) * 65 + wc * 32 + 16 * fj + l15] = acc[fj][j];
        __syncthreads();
        for (int e = tid; e < 2048; e += 256) {
            int mi = e & 31, ni = e >> 5;
            int n = bn + ni;
            int h = (n >> 5) & 7, d = n & 31;
            Vt[(size_t)(h * 32 + d) * NSEQ + bm + mi] = __float2bfloat16(vtile[mi * 65 + ni]);
        }
        return;
    }
    #pragma unroll
    for (int fj = 0; fj < 2; ++fj)
    #pragma unroll
    for (int j = 0; j < 4; ++j) {
        int m = bm + wr * 16 + 4 * g + j;
        int n = bn + wc * 32 + 16 * fj + l15;
        float v = acc[fj][j];
        int which = n >> 8, h = (n >> 5) & 7, d = n & 31;
        // Q pre-scaled into log2 domain for exp2-based softmax
        if (which == 0) Qb[((size_t)(h * NSEQ + m) << 5) + d] = __float2bfloat16(v * (SCALE * LOG2E));
        else            Kb[((size_t)(h * NSEQ + m) << 5) + d] = __float2bfloat16(v);
    }
}

// ---------------- flash attention, kv split 6 ways across blocks ----------------
// log2-domain softmax (Q and bias pre-scaled by log2e); defer-max rescale.
__global__ __launch_bounds__(256) void attn_kernel(
    const __hip_bfloat16* __restrict__ Q,
    const __hip_bfloat16* __restrict__ Kb,
    const __hip_bfloat16* __restrict__ Vt,     // [8][32][2304]
    const float* __restrict__ btabT,           // [8][9025], log2 domain
    float* __restrict__ Pm, float* __restrict__ Pl,
    __hip_bfloat16* __restrict__ PO)           // [6][8][2304][32]
{
    __shared__ float bias_l[10 * 96];
    __shared__ __hip_bfloat16 P_lds[4][16][72];

    int bid = blockIdx.x;
    int h = bid / (36 * KVS);
    int r = bid - h * (36 * KVS);
    int qt = r / KVS, kvq = r - qt * KVS;
    int tid = threadIdx.x;
    int w = tid >> 6, lane = tid & 63, l15 = lane & 15, g = lane >> 4;

    int q0 = qt * 64;
    int i1min = q0 / 48, i1max = (q0 + 63) / 48;
    int i2min = kvq * 8;                 // 384 kv rows = 8 image rows exactly
    int dimin = i1min - (i2min + 7);
    int nrow = (i1max - i1min) + 8;      // <= 9

    for (int i = tid; i < nrow * 95; i += 256) {
        int rr = i / 95, cc = i - rr * 95;
        bias_l[rr * 96 + cc] = btabT[h * 9025 + (dimin + rr + 47) * 95 + cc];
    }
    __syncthreads();

    int qrow = q0 + w * 16 + l15;
    int i1 = qrow / 48, j1 = qrow - i1 * 48;
    int laneBase = (i1 - dimin) * 96 + j1 + 47;
    bf16x8 qf = *reinterpret_cast<const bf16x8*>(Q + ((size_t)(h * NSEQ + qrow) << 5) + 8 * g);

    float m_st = -1e30f, l_st = 0.f;
    f32x4 o0 = (f32x4){0.f, 0.f, 0.f, 0.f};
    f32x4 o1 = (f32x4){0.f, 0.f, 0.f, 0.f};
    const f32x4 zero = (f32x4){0.f, 0.f, 0.f, 0.f};
    int kvbase = kvq * 384;

    for (int t = 0; t < 6; ++t) {
        int kv0 = kvbase + t * 64;
        bf16x8 vf[4];
        #pragma unroll
        for (int u = 0; u < 4; ++u) {
            int dt = u >> 1, hh = u & 1;
            vf[u] = *reinterpret_cast<const bf16x8*>(
                Vt + (size_t)((h << 5) + 16 * dt + l15) * NSEQ + kv0 + 32 * hh + 8 * g);
        }
        f32x4 st[4];
        #pragma unroll
        for (int s = 0; s < 4; ++s) {
            bf16x8 kf = *reinterpret_cast<const bf16x8*>(
                Kb + ((size_t)(h * NSEQ + kv0 + 16 * s + l15) << 5) + 8 * g);
            st[s] = MFMA16(kf, qf, zero);   // S^T[kv][q], log2 domain
        }
        float mx = -1e30f;
        #pragma unroll
        for (int s = 0; s < 4; ++s) {
            int kvb = kv0 + 16 * s + 4 * g;
            int i2 = kvb / 48;
            int j2b = kvb - 48 * i2;
            int sub = laneBase - i2 * 96 - j2b;
            #pragma unroll
            for (int j = 0; j < 4; ++j) {
                int idx = sub - j - ((j2b + j >= 48) ? 48 : 0);
                float sv = st[s][j] + bias_l[idx];
                st[s][j] = sv;
                mx = fmaxf(mx, sv);
            }
        }
        mx = fmaxf(mx, __shfl_xor(mx, 16));
        mx = fmaxf(mx, __shfl_xor(mx, 32));
        // defer-max: skip rescale while the row max hasn't grown past THR
        bool resc = !__all(mx <= m_st + DEFER_THR);
        float mn = resc ? fmaxf(m_st, mx) : m_st;
        float rs = 0.f;
        #pragma unroll
        for (int s = 0; s < 4; ++s)
            #pragma unroll
            for (int j = 0; j < 4; ++j) {
                float e = exp2f(st[s][j] - mn);
                st[s][j] = e;
                rs += e;
            }
        rs += __shfl_xor(rs, 16);
        rs += __shfl_xor(rs, 32);
        if (resc) {
            float sc = exp2f(m_st - mn);
            l_st = l_st * sc + rs;
            m_st = mn;
            float scr[4];
            #pragma unroll
            for (int j = 0; j < 4; ++j) scr[j] = __shfl(sc, 4 * g + j);
            #pragma unroll
            for (int j = 0; j < 4; ++j) { o0[j] *= scr[j]; o1[j] *= scr[j]; }
        } else {
            l_st += rs;
        }
        #pragma unroll
        for (int s = 0; s < 4; ++s) {
            bf16x4 pk = { (__bf16)st[s][0], (__bf16)st[s][1], (__bf16)st[s][2], (__bf16)st[s][3] };
            *reinterpret_cast<bf16x4*>(&P_lds[w][l15][16 * s + 4 * g]) = pk;
        }
        #pragma unroll
        for (int hh = 0; hh < 2; ++hh) {
            bf16x8 pf = *reinterpret_cast<const bf16x8*>(&P_lds[w][l15][32 * hh + 8 * g]);
            o0 = MFMA16(pf, vf[hh], o0);
            o1 = MFMA16(pf, vf[2 + hh], o1);
        }
    }

    size_t mb = (size_t)(kvq * 8 + h) * NSEQ;
    if (g == 0) { Pm[mb + qrow] = m_st; Pl[mb + qrow] = l_st; }
    #pragma unroll
    for (int dt = 0; dt < 2; ++dt)
        #pragma unroll
        for (int j = 0; j < 4; ++j) {
            int row = q0 + w * 16 + 4 * g + j;
            PO[(mb + row) * 32 + 16 * dt + l15] =
                __float2bfloat16(dt == 0 ? o0[j] : o1[j]);
        }
}

// ---------------- fused merge + proj + residual + LN2 ----------------
// grid 144 blocks (16 rows each), 512 thr = 8 waves, depth-2 B pipeline.
__global__ __launch_bounds__(512) void proj_kernel(
    const __hip_bfloat16* __restrict__ PO, const float* __restrict__ Pm,
    const float* __restrict__ Pl, const __hip_bfloat16* __restrict__ BT,
    const float* __restrict__ bproj, const float* __restrict__ x,
    const float* __restrict__ g2, const float* __restrict__ b2,
    float* __restrict__ x2, __hip_bfloat16* __restrict__ t2)
{
    __shared__ char smem[16 * 512];    // merged A-tile [16][256] bf16 swizzled
    __shared__ float redS[8][16], redQ[8][16], muA[16], rsA[16];
    int tid = threadIdx.x;
    int q0 = blockIdx.x * 16;

    // --- merge prologue (log2-domain m) ---
    {
        int row = tid >> 5;            // 0..15
        int c0  = (tid & 31) * 8;
        int h = c0 >> 5, d = c0 & 31;
        float m[KVS], l[KVS], a[KVS];
        #pragma unroll
        for (int k = 0; k < KVS; ++k) {
            size_t mb = (size_t)(k * 8 + h) * NSEQ + q0 + row;
            m[k] = Pm[mb]; l[k] = Pl[mb];
        }
        float M = m[0];
        #pragma unroll
        for (int k = 1; k < KVS; ++k) M = fmaxf(M, m[k]);
        float L = 0.f;
        #pragma unroll
        for (int k = 0; k < KVS; ++k) { a[k] = exp2f(m[k] - M); L += a[k] * l[k]; }
        float inv = 1.f / L;
        float o[8] = {0.f, 0.f, 0.f, 0.f, 0.f, 0.f, 0.f, 0.f};
        #pragma unroll
        for (int k = 0; k < KVS; ++k) {
            bf16x8 po = *reinterpret_cast<const bf16x8*>(
                PO + ((size_t)(k * 8 + h) * NSEQ + q0 + row) * 32 + d);
            #pragma unroll
            for (int e = 0; e < 8; ++e) o[e] += a[k] * (float)po[e];
        }
        bf16x8 pk;
        #pragma unroll
        for (int e = 0; e < 8; ++e) pk[e] = (__bf16)(o[e] * inv);
        *reinterpret_cast<bf16x8*>(smem + SWZ(row, c0 * 2)) = pk;
    }
    __syncthreads();

    // --- GEMM: wave w covers cols w*32..+31 (FM=1, FN=2) ---
    int w = tid >> 6, lane = tid & 63, l15 = lane & 15, g = lane >> 4;
    f32x4 acc[2];
    acc[0] = (f32x4){0.f, 0.f, 0.f, 0.f};
    acc[1] = (f32x4){0.f, 0.f, 0.f, 0.f};
    const __hip_bfloat16* Brow = BT + (size_t)(w * 32 + l15) * 256 + 8 * g;
    bf16x8 p0[2][2], p1[2][2];

#define PLOADB(dst, kb) { \
    _Pragma("unroll") for (int ks = 0; ks < 2; ++ks) \
    _Pragma("unroll") for (int fj = 0; fj < 2; ++fj) \
        dst[ks][fj] = *reinterpret_cast<const bf16x8*>(Brow + (size_t)16 * fj * 256 + (kb) + 32 * ks); }
#define PCOMP(src, kb) { \
    _Pragma("unroll") for (int ks = 0; ks < 2; ++ks) { \
        bf16x8 af = *reinterpret_cast<const bf16x8*>(smem + SWZ(l15, 2 * ((kb) + 32 * ks + 8 * g))); \
        _Pragma("unroll") for (int fj = 0; fj < 2; ++fj) \
            acc[fj] = MFMA16(af, src[ks][fj], acc[fj]); } }

    PLOADB(p0, 0);
    PLOADB(p1, 64);
    PCOMP(p0, 0);
    PLOADB(p0, 128);
    PCOMP(p1, 64);
    PLOADB(p1, 192);
    PCOMP(p0, 128);
    PCOMP(p1, 192);
#undef PLOADB
#undef PCOMP

    // --- epilogue: residual + LN2 ---
    float rr[2][4];
    float s[4] = {0.f, 0.f, 0.f, 0.f}, sq[4] = {0.f, 0.f, 0.f, 0.f};
    #pragma unroll
    for (int fj = 0; fj < 2; ++fj)
        #pragma unroll
        for (int j = 0; j < 4; ++j) {
            int mrow = 4 * g + j;
            int n = w * 32 + 16 * fj + l15;
            float v = acc[fj][j] + bproj[n] + x[(size_t)(q0 + mrow) * 256 + n];
            x2[(size_t)(q0 + mrow) * 256 + n] = v;
            rr[fj][j] = v;
            s[j] += v; sq[j] += v * v;
        }
    #pragma unroll
    for (int mask = 1; mask <= 8; mask <<= 1)
        #pragma unroll
        for (int j = 0; j < 4; ++j) {
            s[j]  += __shfl_xor(s[j],  mask);
            sq[j] += __shfl_xor(sq[j], mask);
        }
    if (l15 == 0)
        #pragma unroll
        for (int j = 0; j < 4; ++j) { redS[w][4 * g + j] = s[j]; redQ[w][4 * g + j] = sq[j]; }
    __syncthreads();
    if (tid < 16) {
        float S = 0.f, Qq = 0.f;
        #pragma unroll
        for (int ww = 0; ww < 8; ++ww) { S += redS[ww][tid]; Qq += redQ[ww][tid]; }
        float mu = S * (1.f / 256.f);
        float var = Qq * (1.f / 256.f) - mu * mu;
        muA[tid] = mu;
        rsA[tid] = rsqrtf(var + 1e-5f);
    }
    __syncthreads();
    #pragma unroll
    for (int fj = 0; fj < 2; ++fj)
        #pragma unroll
        for (int j = 0; j < 4; ++j) {
            int mrow = 4 * g + j;
            int n = w * 32 + 16 * fj + l15;
            float tv = (rr[fj][j] - muA[mrow]) * rsA[mrow] * g2[n] + b2[n];
            t2[(size_t)(q0 + mrow) * 256 + n] = __float2bfloat16(tv);
        }
}

// ---------------- MLP GEMMs, register-pipelined K loop ----------------
// EPI 2: fc1 + bias + gelu (bf16 out)   EPI 3: fc2 + bias + residual (f32 out)
template <int EPI, int NN, int KTOT, int FM, int FN, int WR, int WC>
__global__ __launch_bounds__(256) void gemm_kernel(
    const __hip_bfloat16* __restrict__ A,
    const __hip_bfloat16* __restrict__ BT,
    const float* __restrict__ bias,
    const float* __restrict__ resid,
    void* __restrict__ out0)
{
    constexpr int BM = WR * FM * 16, BN = WC * FN * 16;
    constexpr int NCH = KTOT / 64;              // 64-wide K chunks
    constexpr int NBUF = (KTOT >= 512) ? 3 : 2; // pipeline depth
    int bm = blockIdx.y * BM, bn = blockIdx.x * BN;
    int tid = threadIdx.x;
    int w = tid >> 6, lane = tid & 63, l15 = lane & 15, g = lane >> 4;
    int wr = w / WC, wc = w % WC;

    f32x4 acc[FM][FN];
    #pragma unroll
    for (int i = 0; i < FM; ++i)
        #pragma unroll
        for (int j = 0; j < FN; ++j) acc[i][j] = (f32x4){0.f, 0.f, 0.f, 0.f};

    const __hip_bfloat16* Arow = A  + (size_t)(bm + wr * FM * 16 + l15) * KTOT + 8 * g;
    const __hip_bfloat16* Brow = BT + (size_t)(bn + wc * FN * 16 + l15) * KTOT + 8 * g;

    bf16x8 ab[NBUF][2][FM], bb[NBUF][2][FN];

#define LOADC(ib, kb) { \
    _Pragma("unroll") for (int ks = 0; ks < 2; ++ks) { \
        _Pragma("unroll") for (int i = 0; i < FM; ++i) \
            ab[ib][ks][i] = *reinterpret_cast<const bf16x8*>(Arow + (size_t)16 * i * KTOT + (kb) + 32 * ks); \
        _Pragma("unroll") for (int j2 = 0; j2 < FN; ++j2) \
            bb[ib][ks][j2] = *reinterpret_cast<const bf16x8*>(Brow + (size_t)16 * j2 * KTOT + (kb) + 32 * ks); } }
#define COMPC(ib) { \
    _Pragma("unroll") for (int ks = 0; ks < 2; ++ks) \
        _Pragma("unroll") for (int i = 0; i < FM; ++i) \
            _Pragma("unroll") for (int j2 = 0; j2 < FN; ++j2) \
                acc[i][j2] = MFMA16(ab[ib][ks][i], bb[ib][ks][j2], acc[i][j2]); }

    #pragma unroll
    for (int ib = 0; ib < NBUF; ++ib) LOADC(ib, 64 * ib);
    #pragma unroll
    for (int t = 0; t < NCH; ++t) {
        COMPC(t % NBUF);
        if (t + NBUF < NCH) LOADC(t % NBUF, 64 * (t + NBUF));
    }
#undef LOADC
#undef COMPC

    #pragma unroll
    for (int fi = 0; fi < FM; ++fi)
    #pragma unroll
    for (int fj = 0; fj < FN; ++fj)
    #pragma unroll
    for (int j = 0; j < 4; ++j) {
        int m = bm + wr * FM * 16 + 16 * fi + 4 * g + j;
        int n = bn + wc * FN * 16 + 16 * fj + l15;
        float v = acc[fi][fj][j];
        if constexpr (EPI == 2) {
            float r = v + bias[n];
            r = 0.5f * r * (1.f + erff(r * 0.70710678118654752f));
            ((__hip_bfloat16*)out0)[(size_t)m * NN + n] = __float2bfloat16(r);
        } else {
            ((float*)out0)[(size_t)m * 256 + n] = v + bias[n] + resid[(size_t)m * 256 + n];
        }
    }
}

// ---------------- launch ----------------
extern "C" void kernel_launch(void* const* d_in, const int* in_sizes, int n_in,
                              void* d_out, int out_size, void* d_ws, size_t ws_size,
                              hipStream_t stream)
{
    const float* x      = (const float*)d_in[0];
    const float* gamma1 = (const float*)d_in[1];
    const float* beta1  = (const float*)d_in[2];
    const float* w_qkv  = (const float*)d_in[3];
    const float* w_proj = (const float*)d_in[4];
    const float* b_proj = (const float*)d_in[5];
    const float* btab   = (const float*)d_in[6];
    const float* gamma2 = (const float*)d_in[7];
    const float* beta2  = (const float*)d_in[8];
    const float* w_fc1  = (const float*)d_in[9];
    const float* b_fc1  = (const float*)d_in[10];
    const float* w_fc2  = (const float*)d_in[11];
    const float* b_fc2  = (const float*)d_in[12];
    // d_in[13] rel_idx: recomputed analytically in-kernel.

    char* ws = (char*)d_ws;
    size_t off = 0;
    auto alloc = [&](size_t bytes) -> void* {
        void* p = ws + off;
        off += (bytes + 255) & ~(size_t)255;
        return p;
    };
    __hip_bfloat16* wqkvT = (__hip_bfloat16*)alloc((size_t)768 * 256 * 2);
    __hip_bfloat16* wprojT= (__hip_bfloat16*)alloc((size_t)256 * 256 * 2);
    __hip_bfloat16* wfc1T = (__hip_bfloat16*)alloc((size_t)1024 * 256 * 2);
    __hip_bfloat16* wfc2T = (__hip_bfloat16*)alloc((size_t)256 * 1024 * 2);
    float*          btabT = (float*)alloc((size_t)8 * 9025 * 4);
    __hip_bfloat16* Qb    = (__hip_bfloat16*)alloc((size_t)8 * NSEQ * 32 * 2);
    __hip_bfloat16* Kbuf  = (__hip_bfloat16*)alloc((size_t)8 * NSEQ * 32 * 2);
    __hip_bfloat16* Vt    = (__hip_bfloat16*)alloc((size_t)8 * 32 * NSEQ * 2);
    float*          x2    = (float*)alloc((size_t)NSEQ * 256 * 4);
    __hip_bfloat16* t2    = (__hip_bfloat16*)alloc((size_t)NSEQ * 256 * 2);
    float*          Pm    = (float*)alloc((size_t)KVS * 8 * NSEQ * 4);
    float*          Pl    = (float*)alloc((size_t)KVS * 8 * NSEQ * 4);
    __hip_bfloat16* PO    = (__hip_bfloat16*)alloc((size_t)KVS * 8 * NSEQ * 32 * 2);
    __hip_bfloat16* hb    = (__hip_bfloat16*)alloc((size_t)NSEQ * 1024 * 2);

    prep_kernel<<<dim3(839), dim3(256), 0, stream>>>(
        w_qkv, w_proj, w_fc1, w_fc2, btab, wqkvT, wprojT, wfc1T, wfc2T, btabT);

    qkv_ln_kernel<<<dim3(12, 72), dim3(256), 0, stream>>>(
        x, gamma1, beta1, wqkvT, Qb, Kbuf, Vt);

    attn_kernel<<<dim3(8 * 36 * KVS), dim3(256), 0, stream>>>(
        Qb, Kbuf, Vt, btabT, Pm, Pl, PO);

    proj_kernel<<<dim3(144), dim3(512), 0, stream>>>(
        PO, Pm, Pl, wprojT, b_proj, x, gamma2, beta2, x2, t2);

    // fc1: M=2304 N=1024 K=256, 64x32 blocks, 4 waves (FM=2, FN=1)
    gemm_kernel<2, 1024, 256, 2, 1, 2, 2><<<dim3(32, 36), dim3(256), 0, stream>>>(
        t2, wfc1T, b_fc1, nullptr, hb);

    // fc2: M=2304 N=256 K=1024, 64x16 blocks, 4 waves, depth-3 pipeline
    gemm_kernel<3, 256, 1024, 1, 1, 4, 1><<<dim3(16, 36), dim3(256), 0, stream>>>(
        hb, wfc2T, b_fc2, x2, d_out);
}

// Round 6
// 196.203 us; speedup vs baseline: 1.0791x; 1.0565x over previous
//
#include <hip/hip_runtime.h>
#include <hip/hip_bf16.h>

// ---------------- types ----------------
typedef __bf16 bf16x8 __attribute__((__ext_vector_type__(8)));
typedef __bf16 bf16x4 __attribute__((__ext_vector_type__(4)));
typedef float  f32x4  __attribute__((__ext_vector_type__(4)));

#define MFMA16(a, b, c) __builtin_amdgcn_mfma_f32_16x16x32_bf16((a), (b), (c), 0, 0, 0)

static constexpr int   NSEQ  = 2304;   // 48*48
static constexpr float SCALE = 0.17677669529663687f;  // 32^-0.5
static constexpr float LOG2E = 1.44269504088896340736f;
static constexpr int   KVS   = 6;      // kv split factor
static constexpr float DEFER_THR = 11.5f;  // log2-domain defer-max threshold

// XOR swizzle for [rows][256] bf16 LDS tiles (row stride 512B).
#define SWZ(row, colByte) ((row) * 512 + ((colByte) ^ (((row) & 7) << 4)))

// ---------------- weight transpose + f32->bf16 (+ bias table transpose) ----------------
__global__ __launch_bounds__(256) void prep_kernel(
    const float* __restrict__ wqkv, const float* __restrict__ wproj,
    const float* __restrict__ wfc1, const float* __restrict__ wfc2,
    const float* __restrict__ btab,
    __hip_bfloat16* __restrict__ oqkv, __hip_bfloat16* __restrict__ oproj,
    __hip_bfloat16* __restrict__ ofc1, __hip_bfloat16* __restrict__ ofc2,
    float* __restrict__ btabT)
{
    int b = blockIdx.x;
    int tid = threadIdx.x;
    if (b >= 768) {   // bias table [9025][8] -> [8][9025], pre-scaled to log2 domain
        int base = (b - 768) * 1024;
        for (int k = tid; k < 1024; k += 256) {
            int e = base + k;
            if (e < 72200) { int i = e >> 3, hh = e & 7; btabT[hh * 9025 + i] = btab[e] * LOG2E; }
        }
        return;
    }
    const float* src; __hip_bfloat16* dst; int K, N, t;
    if (b < 192)      { src = wqkv;  dst = oqkv;  K = 256;  N = 768;  t = b;       }
    else if (b < 256) { src = wproj; dst = oproj; K = 256;  N = 256;  t = b - 192; }
    else if (b < 512) { src = wfc1;  dst = ofc1;  K = 256;  N = 1024; t = b - 256; }
    else              { src = wfc2;  dst = ofc2;  K = 1024; N = 256;  t = b - 512; }
    int ntn = N >> 5;
    int tk = t / ntn, tn = t % ntn;
    __shared__ float tile[32][33];
    int tx = tid & 31, ty = tid >> 5;   // 32 x 8
    #pragma unroll
    for (int r = 0; r < 4; ++r)
        tile[ty + 8 * r][tx] = src[(size_t)(tk * 32 + ty + 8 * r) * N + tn * 32 + tx];
    __syncthreads();
    #pragma unroll
    for (int r = 0; r < 4; ++r)
        dst[(size_t)(tn * 32 + ty + 8 * r) * K + tk * 32 + tx] =
            __float2bfloat16(tile[tx][ty + 8 * r]);
}

// ---------------- fused LN1 + QKV GEMM ----------------
// grid (12, 144): 16 rows x 64 cols of [Q|K|V]. 4 waves (16 cols each), depth-2 B pipeline.
__global__ __launch_bounds__(256) void qkv_ln_kernel(
    const float* __restrict__ x, const float* __restrict__ g1,
    const float* __restrict__ b1, const __hip_bfloat16* __restrict__ BT,
    __hip_bfloat16* __restrict__ Qb, __hip_bfloat16* __restrict__ Kb,
    __hip_bfloat16* __restrict__ Vt)
{
    __shared__ char smem[16 * 512];    // A-tile [16][256] bf16 swizzled; V blocks reuse
    int tid = threadIdx.x;
    int bn = blockIdx.x * 64, bm = blockIdx.y * 16;

    // --- LN prologue: 16 lanes per row ---
    {
        int row = tid >> 4, part = tid & 15;
        const float* xr = x + (size_t)(bm + row) * 256 + part * 16;
        float vals[16];
        float s = 0.f, s2 = 0.f;
        #pragma unroll
        for (int i = 0; i < 4; ++i) {
            f32x4 v4 = *reinterpret_cast<const f32x4*>(xr + 4 * i);
            #pragma unroll
            for (int e = 0; e < 4; ++e) {
                vals[4 * i + e] = v4[e];
                s += v4[e]; s2 += v4[e] * v4[e];
            }
        }
        s  += __shfl_xor(s, 1);  s  += __shfl_xor(s, 2);
        s  += __shfl_xor(s, 4);  s  += __shfl_xor(s, 8);
        s2 += __shfl_xor(s2, 1); s2 += __shfl_xor(s2, 2);
        s2 += __shfl_xor(s2, 4); s2 += __shfl_xor(s2, 8);
        float mu   = s * (1.f / 256.f);
        float var  = s2 * (1.f / 256.f) - mu * mu;
        float rstd = rsqrtf(var + 1e-5f);
        #pragma unroll
        for (int i = 0; i < 4; ++i) {
            int c = part * 16 + 4 * i;
            f32x4 gv = *reinterpret_cast<const f32x4*>(g1 + c);
            f32x4 bv = *reinterpret_cast<const f32x4*>(b1 + c);
            bf16x4 pk;
            #pragma unroll
            for (int e = 0; e < 4; ++e)
                pk[e] = (__bf16)((vals[4 * i + e] - mu) * rstd * gv[e] + bv[e]);
            *reinterpret_cast<bf16x4*>(smem + SWZ(row, c * 2)) = pk;
        }
    }
    __syncthreads();

    // --- GEMM: wave w covers cols bn + w*16 ---
    int w = tid >> 6, lane = tid & 63, l15 = lane & 15, g = lane >> 4;
    f32x4 acc = (f32x4){0.f, 0.f, 0.f, 0.f};
    const __hip_bfloat16* Brow = BT + (size_t)(bn + w * 16 + l15) * 256 + 8 * g;
    bf16x8 p0[2], p1[2];

#define QLOADB(dst, kb) { \
    _Pragma("unroll") for (int ks = 0; ks < 2; ++ks) \
        dst[ks] = *reinterpret_cast<const bf16x8*>(Brow + (kb) + 32 * ks); }
#define QCOMP(src, kb) { \
    _Pragma("unroll") for (int ks = 0; ks < 2; ++ks) { \
        bf16x8 af = *reinterpret_cast<const bf16x8*>(smem + SWZ(l15, 2 * ((kb) + 32 * ks + 8 * g))); \
        acc = MFMA16(af, src[ks], acc); } }

    QLOADB(p0, 0);
    QLOADB(p1, 64);
    QCOMP(p0, 0);
    QLOADB(p0, 128);
    QCOMP(p1, 64);
    QLOADB(p1, 192);
    QCOMP(p0, 128);
    QCOMP(p1, 192);
#undef QLOADB
#undef QCOMP

    // --- epilogue ---
    if (bn >= 512) {   // V: LDS transpose for coalesced [h][d][n] stores
        __syncthreads();
        float* vtile = (float*)smem;   // [16][65]
        #pragma unroll
        for (int j = 0; j < 4; ++j)
            vtile[(4 * g + j) * 65 + w * 16 + l15] = acc[j];
        __syncthreads();
        for (int e = tid; e < 1024; e += 256) {
            int mi = e & 15, ni = e >> 4;
            int n = bn + ni;
            int h = (n >> 5) & 7, d = n & 31;
            Vt[(size_t)(h * 32 + d) * NSEQ + bm + mi] = __float2bfloat16(vtile[mi * 65 + ni]);
        }
        return;
    }
    #pragma unroll
    for (int j = 0; j < 4; ++j) {
        int m = bm + 4 * g + j;
        int n = bn + w * 16 + l15;
        float v = acc[j];
        int which = n >> 8, h = (n >> 5) & 7, d = n & 31;
        // Q pre-scaled into log2 domain for exp2-based softmax
        if (which == 0) Qb[((size_t)(h * NSEQ + m) << 5) + d] = __float2bfloat16(v * (SCALE * LOG2E));
        else            Kb[((size_t)(h * NSEQ + m) << 5) + d] = __float2bfloat16(v);
    }
}

// ---------------- flash attention, kv split 6 ways across blocks ----------------
// log2-domain softmax; defer-max with lane-partial l; K-tile prefetch; reversed bias LDS.
__global__ __launch_bounds__(256) void attn_kernel(
    const __hip_bfloat16* __restrict__ Q,
    const __hip_bfloat16* __restrict__ Kb,
    const __hip_bfloat16* __restrict__ Vt,     // [8][32][2304]
    const float* __restrict__ btabT,           // [8][9025], log2 domain
    float* __restrict__ Pm, float* __restrict__ Pl,
    __hip_bfloat16* __restrict__ PO)           // [6][8][2304][32]
{
    __shared__ float bias_l[10 * 96];          // REVERSED cols: addr = rr*96 + 47 - j1 + j2
    __shared__ __hip_bfloat16 P_lds[4][16][72];

    int bid = blockIdx.x;
    int h = bid / (36 * KVS);
    int r = bid - h * (36 * KVS);
    int qt = r / KVS, kvq = r - qt * KVS;
    int tid = threadIdx.x;
    int w = tid >> 6, lane = tid & 63, l15 = lane & 15, g = lane >> 4;

    int q0 = qt * 64;
    int i1min = q0 / 48, i1max = (q0 + 63) / 48;
    int dimin = i1min - (kvq * 8 + 7);
    int nrow = (i1max - i1min) + 8;      // <= 10

    for (int i = tid; i < nrow * 95; i += 256) {
        int rr = i / 95, cc = i - rr * 95;
        bias_l[rr * 96 + 94 - cc] = btabT[h * 9025 + (dimin + rr + 47) * 95 + cc];
    }
    __syncthreads();

    int qrow = q0 + w * 16 + l15;
    int i1 = qrow / 48, j1 = qrow - i1 * 48;
    int colBase = (i1 - dimin) * 96 + 47 - j1;   // addr = colBase - 96*i2 + j2
    bf16x8 qf = *reinterpret_cast<const bf16x8*>(Q + ((size_t)(h * NSEQ + qrow) << 5) + 8 * g);

    float m_st = -1e30f, l_st = 0.f;   // l_st: lane-partial (quarter-row) sum
    f32x4 o0 = (f32x4){0.f, 0.f, 0.f, 0.f};
    f32x4 o1 = (f32x4){0.f, 0.f, 0.f, 0.f};
    const f32x4 zero = (f32x4){0.f, 0.f, 0.f, 0.f};
    int kvbase = kvq * 384;

    const __hip_bfloat16* Kbase = Kb + ((size_t)(h * NSEQ + l15) << 5) + 8 * g;

    bf16x8 kf[4], kn[4];
    #pragma unroll
    for (int s = 0; s < 4; ++s)
        kn[s] = *reinterpret_cast<const bf16x8*>(Kbase + ((size_t)(kvbase + 16 * s) << 5));

    for (int t = 0; t < 6; ++t) {
        int kv0 = kvbase + t * 64;
        #pragma unroll
        for (int s = 0; s < 4; ++s) kf[s] = kn[s];
        // V loads early (consumed after softmax)
        bf16x8 vf[4];
        #pragma unroll
        for (int u = 0; u < 4; ++u) {
            int dt = u >> 1, hh = u & 1;
            vf[u] = *reinterpret_cast<const bf16x8*>(
                Vt + (size_t)((h << 5) + 16 * dt + l15) * NSEQ + kv0 + 32 * hh + 8 * g);
        }
        // prefetch next K tile (consumed next iteration)
        if (t < 5) {
            #pragma unroll
            for (int s = 0; s < 4; ++s)
                kn[s] = *reinterpret_cast<const bf16x8*>(
                    Kbase + ((size_t)(kv0 + 64 + 16 * s) << 5));
        }
        f32x4 st[4];
        #pragma unroll
        for (int s = 0; s < 4; ++s)
            st[s] = MFMA16(kf[s], qf, zero);   // S^T[kv][q], log2 domain

        // bias add (reversed-layout, 1 base addr per strip) + local max tree
        float p[4][4];
        float ms[4];
        #pragma unroll
        for (int s = 0; s < 4; ++s) {
            int kvb = kv0 + 16 * s + 4 * g;
            int i2 = kvb / 48;
            int j2b = kvb - 48 * i2;
            int a0 = colBase - 96 * i2 + j2b;
            #pragma unroll
            for (int j = 0; j < 4; ++j) {
                int addr = a0 + j - ((j2b + j >= 48) ? 144 : 0);
                p[s][j] = st[s][j] + bias_l[addr];
            }
            ms[s] = fmaxf(fmaxf(p[s][0], p[s][1]), fmaxf(p[s][2], p[s][3]));
        }
        float mx = fmaxf(fmaxf(ms[0], ms[1]), fmaxf(ms[2], ms[3]));
        // defer-max vote: common path needs NO cross-lane reduce at all
        float mn = m_st;
        if (!__all(mx <= m_st + DEFER_THR)) {
            float mxf = fmaxf(mx, __shfl_xor(mx, 16));
            mxf = fmaxf(mxf, __shfl_xor(mxf, 32));
            mn = fmaxf(m_st, mxf);
            float sc = exp2f(m_st - mn);
            m_st = mn;
            l_st *= sc;
            float scr[4];
            #pragma unroll
            for (int j = 0; j < 4; ++j) scr[j] = __shfl(sc, 4 * g + j);
            #pragma unroll
            for (int j = 0; j < 4; ++j) { o0[j] *= scr[j]; o1[j] *= scr[j]; }
        }
        float rsum[4];
        #pragma unroll
        for (int s = 0; s < 4; ++s) {
            #pragma unroll
            for (int j = 0; j < 4; ++j) p[s][j] = exp2f(p[s][j] - mn);
            rsum[s] = (p[s][0] + p[s][1]) + (p[s][2] + p[s][3]);
        }
        l_st += (rsum[0] + rsum[1]) + (rsum[2] + rsum[3]);
        // P -> LDS (transpose back to [q][kv]); wave-private, no barrier needed
        #pragma unroll
        for (int s = 0; s < 4; ++s) {
            bf16x4 pk = { (__bf16)p[s][0], (__bf16)p[s][1], (__bf16)p[s][2], (__bf16)p[s][3] };
            *reinterpret_cast<bf16x4*>(&P_lds[w][l15][16 * s + 4 * g]) = pk;
        }
        // PV
        #pragma unroll
        for (int hh = 0; hh < 2; ++hh) {
            bf16x8 pf = *reinterpret_cast<const bf16x8*>(&P_lds[w][l15][32 * hh + 8 * g]);
            o0 = MFMA16(pf, vf[hh], o0);
            o1 = MFMA16(pf, vf[2 + hh], o1);
        }
    }

    // final l reduce (once per block instead of per tile)
    float l_red = l_st + __shfl_xor(l_st, 16);
    l_red += __shfl_xor(l_red, 32);

    size_t mb = (size_t)(kvq * 8 + h) * NSEQ;
    if (g == 0) { Pm[mb + qrow] = m_st; Pl[mb + qrow] = l_red; }
    #pragma unroll
    for (int dt = 0; dt < 2; ++dt)
        #pragma unroll
        for (int j = 0; j < 4; ++j) {
            int row = q0 + w * 16 + 4 * g + j;
            PO[(mb + row) * 32 + 16 * dt + l15] =
                __float2bfloat16(dt == 0 ? o0[j] : o1[j]);
        }
}

// ---------------- fused merge + proj + residual (LN2 moved to ln_fc1) ----------------
// grid (4, 144): 16 rows x 64 cols; 4 waves (16 cols each), depth-2 B pipeline.
__global__ __launch_bounds__(256) void proj_kernel(
    const __hip_bfloat16* __restrict__ PO, const float* __restrict__ Pm,
    const float* __restrict__ Pl, const __hip_bfloat16* __restrict__ BT,
    const float* __restrict__ bproj, const float* __restrict__ x,
    float* __restrict__ x2)
{
    __shared__ char smem[16 * 512];    // merged A-tile [16][256] bf16 swizzled
    int tid = threadIdx.x;
    int q0 = blockIdx.y * 16, bn = blockIdx.x * 64;

    // --- merge prologue (each lane: 16 cols of one head) ---
    {
        int row = tid >> 4;            // 0..15
        int c0  = (tid & 15) * 16;
        int h = c0 >> 5, d = c0 & 31;  // d = 0 or 16
        float m[KVS], l[KVS], a[KVS];
        #pragma unroll
        for (int k = 0; k < KVS; ++k) {
            size_t mb = (size_t)(k * 8 + h) * NSEQ + q0 + row;
            m[k] = Pm[mb]; l[k] = Pl[mb];
        }
        float M = m[0];
        #pragma unroll
        for (int k = 1; k < KVS; ++k) M = fmaxf(M, m[k]);
        float L = 0.f;
        #pragma unroll
        for (int k = 0; k < KVS; ++k) { a[k] = exp2f(m[k] - M); L += a[k] * l[k]; }
        float inv = 1.f / L;
        float o[16];
        #pragma unroll
        for (int e = 0; e < 16; ++e) o[e] = 0.f;
        #pragma unroll
        for (int k = 0; k < KVS; ++k) {
            const __hip_bfloat16* pr = PO + ((size_t)(k * 8 + h) * NSEQ + q0 + row) * 32 + d;
            bf16x8 po0 = *reinterpret_cast<const bf16x8*>(pr);
            bf16x8 po1 = *reinterpret_cast<const bf16x8*>(pr + 8);
            #pragma unroll
            for (int e = 0; e < 8; ++e) {
                o[e]     += a[k] * (float)po0[e];
                o[8 + e] += a[k] * (float)po1[e];
            }
        }
        #pragma unroll
        for (int i = 0; i < 4; ++i) {
            bf16x4 pk;
            #pragma unroll
            for (int e = 0; e < 4; ++e) pk[e] = (__bf16)(o[4 * i + e] * inv);
            *reinterpret_cast<bf16x4*>(smem + SWZ(row, (c0 + 4 * i) * 2)) = pk;
        }
    }
    __syncthreads();

    // --- GEMM: wave w covers cols bn + w*16 ---
    int w = tid >> 6, lane = tid & 63, l15 = lane & 15, g = lane >> 4;
    f32x4 acc = (f32x4){0.f, 0.f, 0.f, 0.f};
    const __hip_bfloat16* Brow = BT + (size_t)(bn + w * 16 + l15) * 256 + 8 * g;
    bf16x8 p0[2], p1[2];

#define PLOADB(dst, kb) { \
    _Pragma("unroll") for (int ks = 0; ks < 2; ++ks) \
        dst[ks] = *reinterpret_cast<const bf16x8*>(Brow + (kb) + 32 * ks); }
#define PCOMP(src, kb) { \
    _Pragma("unroll") for (int ks = 0; ks < 2; ++ks) { \
        bf16x8 af = *reinterpret_cast<const bf16x8*>(smem + SWZ(l15, 2 * ((kb) + 32 * ks + 8 * g))); \
        acc = MFMA16(af, src[ks], acc); } }

    PLOADB(p0, 0);
    PLOADB(p1, 64);
    PCOMP(p0, 0);
    PLOADB(p0, 128);
    PCOMP(p1, 64);
    PLOADB(p1, 192);
    PCOMP(p0, 128);
    PCOMP(p1, 192);
#undef PLOADB
#undef PCOMP

    #pragma unroll
    for (int j = 0; j < 4; ++j) {
        int m = q0 + 4 * g + j;
        int n = bn + w * 16 + l15;
        x2[(size_t)m * 256 + n] = acc[j] + bproj[n] + x[(size_t)m * 256 + n];
    }
}

// ---------------- fused LN2 + fc1 + gelu ----------------
// grid (16, 72): 32 rows x 64 cols of fc1. 4 waves (2x2), depth-2 B pipeline.
__global__ __launch_bounds__(256) void ln_fc1_kernel(
    const float* __restrict__ x2, const float* __restrict__ g2,
    const float* __restrict__ b2, const __hip_bfloat16* __restrict__ BT,
    const float* __restrict__ bfc1, __hip_bfloat16* __restrict__ hb)
{
    __shared__ char smem[32 * 512];    // A-tile [32][256] bf16 swizzled
    int tid = threadIdx.x;
    int bn = blockIdx.x * 64, bm = blockIdx.y * 32;

    // --- LN prologue: 8 lanes per row ---
    {
        int row = tid >> 3, part = tid & 7;
        const float* xr = x2 + (size_t)(bm + row) * 256 + part * 32;
        float vals[32];
        float s = 0.f, s2 = 0.f;
        #pragma unroll
        for (int i = 0; i < 8; ++i) {
            f32x4 v4 = *reinterpret_cast<const f32x4*>(xr + 4 * i);
            #pragma unroll
            for (int e = 0; e < 4; ++e) {
                vals[4 * i + e] = v4[e];
                s += v4[e]; s2 += v4[e] * v4[e];
            }
        }
        s  += __shfl_xor(s, 1);  s  += __shfl_xor(s, 2);  s  += __shfl_xor(s, 4);
        s2 += __shfl_xor(s2, 1); s2 += __shfl_xor(s2, 2); s2 += __shfl_xor(s2, 4);
        float mu   = s * (1.f / 256.f);
        float var  = s2 * (1.f / 256.f) - mu * mu;
        float rstd = rsqrtf(var + 1e-5f);
        #pragma unroll
        for (int i = 0; i < 8; ++i) {
            int c = part * 32 + 4 * i;
            f32x4 gv = *reinterpret_cast<const f32x4*>(g2 + c);
            f32x4 bv = *reinterpret_cast<const f32x4*>(b2 + c);
            bf16x4 pk;
            #pragma unroll
            for (int e = 0; e < 4; ++e)
                pk[e] = (__bf16)((vals[4 * i + e] - mu) * rstd * gv[e] + bv[e]);
            *reinterpret_cast<bf16x4*>(smem + SWZ(row, c * 2)) = pk;
        }
    }
    __syncthreads();

    // --- GEMM: waves 2x2, FM=1, FN=2 ---
    int w = tid >> 6, lane = tid & 63, l15 = lane & 15, g = lane >> 4;
    int wr = w >> 1, wc = w & 1;
    f32x4 acc[2];
    acc[0] = (f32x4){0.f, 0.f, 0.f, 0.f};
    acc[1] = (f32x4){0.f, 0.f, 0.f, 0.f};
    const __hip_bfloat16* Brow = BT + (size_t)(bn + wc * 32 + l15) * 256 + 8 * g;
    bf16x8 p0[2][2], p1[2][2];

#define FLOADB(dst, kb) { \
    _Pragma("unroll") for (int ks = 0; ks < 2; ++ks) \
    _Pragma("unroll") for (int fj = 0; fj < 2; ++fj) \
        dst[ks][fj] = *reinterpret_cast<const bf16x8*>(Brow + (size_t)16 * fj * 256 + (kb) + 32 * ks); }
#define FCOMP(src, kb) { \
    _Pragma("unroll") for (int ks = 0; ks < 2; ++ks) { \
        bf16x8 af = *reinterpret_cast<const bf16x8*>(smem + SWZ(wr * 16 + l15, 2 * ((kb) + 32 * ks + 8 * g))); \
        _Pragma("unroll") for (int fj = 0; fj < 2; ++fj) \
            acc[fj] = MFMA16(af, src[ks][fj], acc[fj]); } }

    FLOADB(p0, 0);
    FLOADB(p1, 64);
    FCOMP(p0, 0);
    FLOADB(p0, 128);
    FCOMP(p1, 64);
    FLOADB(p1, 192);
    FCOMP(p0, 128);
    FCOMP(p1, 192);
#undef FLOADB
#undef FCOMP

    // --- epilogue: bias + fast gelu (tanh form via exp2-sigmoid) ---
    #pragma unroll
    for (int fj = 0; fj < 2; ++fj)
        #pragma unroll
        for (int j = 0; j < 4; ++j) {
            int m = bm + wr * 16 + 4 * g + j;
            int n = bn + wc * 32 + 16 * fj + l15;
            float r = acc[fj][j] + bfc1[n];
            float u = r * (r * r * 0.044715f + 1.f) * -2.302118131f;  // -2*0.79788456*log2e
            float gl = r / (1.f + exp2f(u));
            hb[(size_t)m * 1024 + n] = __float2bfloat16(gl);
        }
}

// ---------------- fc2: C = A[M,1024] @ BT[256,1024]^T + bias + residual ----------------
// grid (16, 72), 128 thr (2 waves, 16 rows each), depth-4 register pipeline.
template <int KTOT, int FM, int FN, int WR, int WC>
__global__ __launch_bounds__(128) void fc2_kernel(
    const __hip_bfloat16* __restrict__ A,
    const __hip_bfloat16* __restrict__ BT,
    const float* __restrict__ bias,
    const float* __restrict__ resid,
    float* __restrict__ out0)
{
    constexpr int BM = WR * FM * 16, BN = WC * FN * 16;
    constexpr int NCH = KTOT / 64;
    constexpr int NBUF = 4;
    int bm = blockIdx.y * BM, bn = blockIdx.x * BN;
    int tid = threadIdx.x;
    int w = tid >> 6, lane = tid & 63, l15 = lane & 15, g = lane >> 4;
    int wr = w / WC, wc = w % WC;

    f32x4 acc[FM][FN];
    #pragma unroll
    for (int i = 0; i < FM; ++i)
        #pragma unroll
        for (int j = 0; j < FN; ++j) acc[i][j] = (f32x4){0.f, 0.f, 0.f, 0.f};

    const __hip_bfloat16* Arow = A  + (size_t)(bm + wr * FM * 16 + l15) * KTOT + 8 * g;
    const __hip_bfloat16* Brow = BT + (size_t)(bn + wc * FN * 16 + l15) * KTOT + 8 * g;

    bf16x8 ab[NBUF][2][FM], bb[NBUF][2][FN];

#define LOADC(ib, kb) { \
    _Pragma("unroll") for (int ks = 0; ks < 2; ++ks) { \
        _Pragma("unroll") for (int i = 0; i < FM; ++i) \
            ab[ib][ks][i] = *reinterpret_cast<const bf16x8*>(Arow + (size_t)16 * i * KTOT + (kb) + 32 * ks); \
        _Pragma("unroll") for (int j2 = 0; j2 < FN; ++j2) \
            bb[ib][ks][j2] = *reinterpret_cast<const bf16x8*>(Brow + (size_t)16 * j2 * KTOT + (kb) + 32 * ks); } }
#define COMPC(ib) { \
    _Pragma("unroll") for (int ks = 0; ks < 2; ++ks) \
        _Pragma("unroll") for (int i = 0; i < FM; ++i) \
            _Pragma("unroll") for (int j2 = 0; j2 < FN; ++j2) \
                acc[i][j2] = MFMA16(ab[ib][ks][i], bb[ib][ks][j2], acc[i][j2]); }

    #pragma unroll
    for (int ib = 0; ib < NBUF; ++ib) LOADC(ib, 64 * ib);
    #pragma unroll
    for (int t = 0; t < NCH; ++t) {
        COMPC(t % NBUF);
        if (t + NBUF < NCH) LOADC(t % NBUF, 64 * (t + NBUF));
    }
#undef LOADC
#undef COMPC

    #pragma unroll
    for (int fi = 0; fi < FM; ++fi)
    #pragma unroll
    for (int fj = 0; fj < FN; ++fj)
    #pragma unroll
    for (int j = 0; j < 4; ++j) {
        int m = bm + wr * FM * 16 + 16 * fi + 4 * g + j;
        int n = bn + wc * FN * 16 + 16 * fj + l15;
        out0[(size_t)m * 256 + n] = acc[fi][fj][j] + bias[n] + resid[(size_t)m * 256 + n];
    }
}

// ---------------- launch ----------------
extern "C" void kernel_launch(void* const* d_in, const int* in_sizes, int n_in,
                              void* d_out, int out_size, void* d_ws, size_t ws_size,
                              hipStream_t stream)
{
    const float* x      = (const float*)d_in[0];
    const float* gamma1 = (const float*)d_in[1];
    const float* beta1  = (const float*)d_in[2];
    const float* w_qkv  = (const float*)d_in[3];
    const float* w_proj = (const float*)d_in[4];
    const float* b_proj = (const float*)d_in[5];
    const float* btab   = (const float*)d_in[6];
    const float* gamma2 = (const float*)d_in[7];
    const float* beta2  = (const float*)d_in[8];
    const float* w_fc1  = (const float*)d_in[9];
    const float* b_fc1  = (const float*)d_in[10];
    const float* w_fc2  = (const float*)d_in[11];
    const float* b_fc2  = (const float*)d_in[12];
    // d_in[13] rel_idx: recomputed analytically in-kernel.

    char* ws = (char*)d_ws;
    size_t off = 0;
    auto alloc = [&](size_t bytes) -> void* {
        void* p = ws + off;
        off += (bytes + 255) & ~(size_t)255;
        return p;
    };
    __hip_bfloat16* wqkvT = (__hip_bfloat16*)alloc((size_t)768 * 256 * 2);
    __hip_bfloat16* wprojT= (__hip_bfloat16*)alloc((size_t)256 * 256 * 2);
    __hip_bfloat16* wfc1T = (__hip_bfloat16*)alloc((size_t)1024 * 256 * 2);
    __hip_bfloat16* wfc2T = (__hip_bfloat16*)alloc((size_t)256 * 1024 * 2);
    float*          btabT = (float*)alloc((size_t)8 * 9025 * 4);
    __hip_bfloat16* Qb    = (__hip_bfloat16*)alloc((size_t)8 * NSEQ * 32 * 2);
    __hip_bfloat16* Kbuf  = (__hip_bfloat16*)alloc((size_t)8 * NSEQ * 32 * 2);
    __hip_bfloat16* Vt    = (__hip_bfloat16*)alloc((size_t)8 * 32 * NSEQ * 2);
    float*          x2    = (float*)alloc((size_t)NSEQ * 256 * 4);
    float*          Pm    = (float*)alloc((size_t)KVS * 8 * NSEQ * 4);
    float*          Pl    = (float*)alloc((size_t)KVS * 8 * NSEQ * 4);
    __hip_bfloat16* PO    = (__hip_bfloat16*)alloc((size_t)KVS * 8 * NSEQ * 32 * 2);
    __hip_bfloat16* hb    = (__hip_bfloat16*)alloc((size_t)NSEQ * 1024 * 2);

    prep_kernel<<<dim3(839), dim3(256), 0, stream>>>(
        w_qkv, w_proj, w_fc1, w_fc2, btab, wqkvT, wprojT, wfc1T, wfc2T, btabT);

    qkv_ln_kernel<<<dim3(12, 144), dim3(256), 0, stream>>>(
        x, gamma1, beta1, wqkvT, Qb, Kbuf, Vt);

    attn_kernel<<<dim3(8 * 36 * KVS), dim3(256), 0, stream>>>(
        Qb, Kbuf, Vt, btabT, Pm, Pl, PO);

    proj_kernel<<<dim3(4, 144), dim3(256), 0, stream>>>(
        PO, Pm, Pl, wprojT, b_proj, x, x2);

    ln_fc1_kernel<<<dim3(16, 72), dim3(256), 0, stream>>>(
        x2, gamma2, beta2, wfc1T, b_fc1, hb);

    fc2_kernel<1024, 1, 1, 2, 1><<<dim3(16, 72), dim3(128), 0, stream>>>(
        hb, wfc2T, b_fc2, x2, (float*)d_out);
}